// Round 20
// baseline (425.535 us; speedup 1.0000x reference)
//
#include <hip/hip_runtime.h>

typedef __attribute__((ext_vector_type(8))) short bf16x8;
typedef __attribute__((ext_vector_type(4))) float floatx4;

__device__ __forceinline__ unsigned short f2bf(float f) {
  unsigned int u = __builtin_bit_cast(unsigned int, f);
  unsigned int r = (u + 0x7fffu + ((u >> 16) & 1u)) >> 16;
  return (unsigned short)r;
}

__device__ __forceinline__ unsigned int pack2(float a, float b) {
  return (unsigned int)f2bf(a) | ((unsigned int)f2bf(b) << 16);
}

__device__ __forceinline__ void gload16(const void* g, void* l) {
  __builtin_amdgcn_global_load_lds(
      (__attribute__((address_space(1))) void*)g,
      (__attribute__((address_space(3))) void*)l, 16, 0, 0);
}

// full-drain barrier (loop top): K(M) prefetch + prev-step LDS reads done.
__device__ __forceinline__ void barrier_v0_lgkm() {
  asm volatile("s_waitcnt vmcnt(0) lgkmcnt(0)" ::: "memory");
  __builtin_amdgcn_s_barrier();
  __builtin_amdgcn_sched_barrier(0);
}

// out = x (residual init), plus f32->bf16 of x, [Wq;Wk] concat, Wv (scaled 1/N)
__global__ __launch_bounds__(256) void convert_all(
    const float4* __restrict__ x4,
    const float4* __restrict__ wq4, const float4* __restrict__ wk4,
    const float4* __restrict__ wv4,
    uint2* __restrict__ xb4, uint2* __restrict__ wqkb4, uint2* __restrict__ wvb4,
    float4* __restrict__ out4)
{
  const int NX = 2 * 2048 * 1024 / 4;
  const int NQK = 8 * 256 * 1024 / 4;
  const int NV = 8 * 1024 * 1024 / 4;
  const int total = NX + NQK + NV;
  const float inv_n = 1.0f / 2048.0f;
  for (int i = blockIdx.x * 256 + threadIdx.x; i < total; i += gridDim.x * 256) {
    float4 f; uint2* dst;
    if (i < NX) {
      f = x4[i]; dst = &xb4[i];
      out4[i] = f;                         // residual init fused here
    } else if (i < NX + NQK) {
      int j = i - NX;
      int c = j & 255;
      int row = j >> 8;
      int h = row >> 8, r = row & 255;
      f = (r < 128) ? wq4[(h * 128 + r) * 256 + c] : wk4[(h * 128 + r - 128) * 256 + c];
      dst = &wqkb4[j];
    } else {
      int j = i - NX - NQK;
      f = wv4[j];
      f.x *= inv_n; f.y *= inv_n; f.z *= inv_n; f.w *= inv_n;  // fold 1/N into V
      dst = &wvb4[j];
    }
    uint2 p; p.x = pack2(f.x, f.y); p.y = pack2(f.z, f.w);
    *dst = p;
  }
}

// init for fallback path
__global__ __launch_bounds__(256) void init_out(const float4* __restrict__ x,
                                                float4* __restrict__ out, int n4) {
  for (int i = blockIdx.x * 256 + threadIdx.x; i < n4; i += gridDim.x * 256)
    out[i] = x[i];
}

// ============ 256x256 8-phase GEMM (guide §5.5 T2+T3+T4+T5 template) ========
__global__ __launch_bounds__(512, 2) void gemm8(
    const unsigned short* __restrict__ xb,
    const unsigned short* __restrict__ Wqkb,
    const unsigned short* __restrict__ Wvb,
    unsigned short* __restrict__ Qb, unsigned short* __restrict__ Kb,
    unsigned short* __restrict__ Vtb)
{
  __shared__ __align__(16) unsigned short LA[2][2][128 * 64]; // [dbuf][half]
  __shared__ __align__(16) unsigned short LB[2][2][128 * 64];
  const int bid = blockIdx.x;
  const int t = threadIdx.x;
  const int l = t & 63, w = t >> 6;
  const int l16 = l & 15, lq = l >> 4;
  const int wm = w & 1, wn = w >> 1;

  const unsigned short *Ag, *Bg;
  unsigned short *C0, *C1; long ld0, ld1; int split;
  if (bid < 128) {
    int z = bid & 15, br = bid >> 4;
    int b = z >> 3, h = z & 7;
    Ag = xb + (long)b * 2048 * 1024 + (long)br * 256 * 1024;
    Bg = Wqkb + (long)h * 256 * 1024;
    C0 = Qb + (long)z * 2048 * 128 + (long)br * 256 * 128;
    C1 = Kb + (long)z * 2048 * 128 + (long)br * 256 * 128;
    ld0 = 128; ld1 = 128; split = 128;
  } else {
    int v = bid - 128;
    int z = v & 15, rc = v >> 4;
    int bx = rc & 3, by = rc >> 2;
    int b = z >> 3, h = z & 7;
    Ag = Wvb + (long)h * 1024 * 1024 + (long)bx * 256 * 1024;
    Bg = xb + (long)b * 2048 * 1024 + (long)by * 256 * 1024;
    C0 = Vtb + (long)z * 1024 * 2048 + (long)bx * 256 * 2048 + by * 256;
    C1 = C0; ld0 = 2048; ld1 = 2048; split = 1 << 30;
  }

  int rr[2], kk[2], cb[2];
#pragma unroll
  for (int i = 0; i < 2; i++) {
    int c = i * 512 + t;
    rr[i] = c >> 3;
    int k8 = c & 7;
    kk[i] = (k8 ^ (((rr[i] >> 2) & 3) << 1)) * 8;
    cb[i] = (i * 512 + w * 64) * 8;
  }
  auto STAGE = [&](const unsigned short* OP, unsigned short* dstbuf, int kt, int half) {
#pragma unroll
    for (int i = 0; i < 2; i++)
      gload16(OP + (long)(half * 128 + rr[i]) * 1024 + kt * 64 + kk[i],
              dstbuf + cb[i]);
  };
  auto RD = [&](const unsigned short* buf, int fr, int ks) -> bf16x8 {
    int r = fr * 16 + l16;
    int k8 = ks * 4 + lq;
    int k8s = k8 ^ (((r >> 2) & 3) << 1);
    return *reinterpret_cast<const bf16x8*>(buf + r * 64 + k8s * 8);
  };

  floatx4 acc[8][4] = {};
  const int bfr = (wn & 1) * 4;

  STAGE(Ag, LA[0][0], 0, 0); STAGE(Ag, LA[0][1], 0, 1);
  STAGE(Bg, LB[0][0], 0, 0); STAGE(Bg, LB[0][1], 0, 1);
  asm volatile("s_waitcnt vmcnt(0)" ::: "memory");
  __builtin_amdgcn_s_barrier();
  __builtin_amdgcn_sched_barrier(0);

  for (int kt = 0; kt < 16; kt++) {
    const int d = kt & 1, nd = d ^ 1;
    const unsigned short* myA = LA[d][wm];
    const unsigned short* myB = LB[d][wn >> 1];
    const bool more = (kt + 1 < 16);
    bf16x8 a0[4][2], a1[4][2], b0[2][2], b1[2][2];

#pragma unroll
    for (int fr = 0; fr < 4; fr++)
#pragma unroll
      for (int ks = 0; ks < 2; ks++) a0[fr][ks] = RD(myA, fr, ks);
#pragma unroll
    for (int fc = 0; fc < 2; fc++)
#pragma unroll
      for (int ks = 0; ks < 2; ks++) b0[fc][ks] = RD(myB, bfr + fc, ks);
    if (more) { STAGE(Ag, LA[nd][0], kt + 1, 0); STAGE(Ag, LA[nd][1], kt + 1, 1); }
    __builtin_amdgcn_s_barrier();
    asm volatile("s_waitcnt lgkmcnt(0)" ::: "memory");
    __builtin_amdgcn_sched_barrier(0);
    __builtin_amdgcn_s_setprio(1);
#pragma unroll
    for (int fr = 0; fr < 4; fr++)
#pragma unroll
      for (int fc = 0; fc < 2; fc++)
#pragma unroll
        for (int ks = 0; ks < 2; ks++)
          acc[fr][fc] = __builtin_amdgcn_mfma_f32_16x16x32_bf16(
              a0[fr][ks], b0[fc][ks], acc[fr][fc], 0, 0, 0);
    __builtin_amdgcn_s_setprio(0);
    __builtin_amdgcn_s_barrier();

#pragma unroll
    for (int fc = 0; fc < 2; fc++)
#pragma unroll
      for (int ks = 0; ks < 2; ks++) b1[fc][ks] = RD(myB, bfr + 2 + fc, ks);
    if (more) { STAGE(Bg, LB[nd][0], kt + 1, 0); STAGE(Bg, LB[nd][1], kt + 1, 1); }
    __builtin_amdgcn_s_barrier();
    asm volatile("s_waitcnt lgkmcnt(0)" ::: "memory");
    __builtin_amdgcn_sched_barrier(0);
    __builtin_amdgcn_s_setprio(1);
#pragma unroll
    for (int fr = 0; fr < 4; fr++)
#pragma unroll
      for (int fc = 0; fc < 2; fc++)
#pragma unroll
        for (int ks = 0; ks < 2; ks++)
          acc[fr][2 + fc] = __builtin_amdgcn_mfma_f32_16x16x32_bf16(
              a0[fr][ks], b1[fc][ks], acc[fr][2 + fc], 0, 0, 0);
    __builtin_amdgcn_s_setprio(0);
    __builtin_amdgcn_s_barrier();

#pragma unroll
    for (int fr = 0; fr < 4; fr++)
#pragma unroll
      for (int ks = 0; ks < 2; ks++) a1[fr][ks] = RD(myA, 4 + fr, ks);
    __builtin_amdgcn_s_barrier();
    asm volatile("s_waitcnt lgkmcnt(0)" ::: "memory");
    __builtin_amdgcn_sched_barrier(0);
    __builtin_amdgcn_s_setprio(1);
#pragma unroll
    for (int fr = 0; fr < 4; fr++)
#pragma unroll
      for (int fc = 0; fc < 2; fc++)
#pragma unroll
        for (int ks = 0; ks < 2; ks++)
          acc[4 + fr][fc] = __builtin_amdgcn_mfma_f32_16x16x32_bf16(
              a1[fr][ks], b0[fc][ks], acc[4 + fr][fc], 0, 0, 0);
    __builtin_amdgcn_s_setprio(0);
    __builtin_amdgcn_s_barrier();

    __builtin_amdgcn_s_setprio(1);
#pragma unroll
    for (int fr = 0; fr < 4; fr++)
#pragma unroll
      for (int fc = 0; fc < 2; fc++)
#pragma unroll
        for (int ks = 0; ks < 2; ks++)
          acc[4 + fr][2 + fc] = __builtin_amdgcn_mfma_f32_16x16x32_bf16(
              a1[fr][ks], b1[fc][ks], acc[4 + fr][2 + fc], 0, 0, 0);
    __builtin_amdgcn_s_setprio(0);
    asm volatile("s_waitcnt vmcnt(0)" ::: "memory");
    __builtin_amdgcn_s_barrier();
    __builtin_amdgcn_sched_barrier(0);
  }

#pragma unroll
  for (int fr = 0; fr < 8; fr++)
#pragma unroll
    for (int fc = 0; fc < 4; fc++)
#pragma unroll
      for (int j = 0; j < 4; j++) {
        int row = wm * 128 + fr * 16 + lq * 4 + j;
        int col = wn * 64 + fc * 16 + l16;
        unsigned short v = f2bf(acc[fr][fc][j]);
        if (col < split) C0[(long)row * ld0 + col] = v;
        else             C1[(long)row * ld1 + (col - split)] = v;
      }
}
// ===========================================================================

// ---------------- fallback (f32-staging) GEMMs, used if ws too small --------
__global__ __launch_bounds__(256) void gemm_bt(
    const float* __restrict__ Abase, long sAb, long sAh,
    const float* __restrict__ Bbase, long sBb, long sBh,
    unsigned short* __restrict__ Cbase, long sC,
    int M, int Nc, int K, int H, float cscale)
{
  int z = blockIdx.z;
  int b = z / H, h = z % H;
  const float* A  = Abase + (long)b * sAb + (long)h * sAh;
  const float* Bm = Bbase + (long)b * sBb + (long)h * sBh;
  unsigned short* C = Cbase + (long)z * sC;
  int tRow = blockIdx.x * 128;
  int tCol = blockIdx.y * 128;
  __shared__ __align__(16) unsigned short LA[128 * 72];
  __shared__ __align__(16) unsigned short LB[128 * 72];
  int t = threadIdx.x;
  int l = t & 63, w = t >> 6;
  int wr = w >> 1, wc = w & 1;
  int l16 = l & 15, lq = l >> 4;
  floatx4 acc[4][4] = {};
  for (int k0 = 0; k0 < K; k0 += 64) {
    __syncthreads();
    for (int i = 0; i < 8; i++) {
      int lin = i * 256 + t;
      int row = lin >> 4;
      int c4  = lin & 15;
      float4 va = *reinterpret_cast<const float4*>(A + (long)(tRow + row) * K + k0 + c4 * 4);
      uint2 pa; pa.x = pack2(va.x, va.y); pa.y = pack2(va.z, va.w);
      *reinterpret_cast<uint2*>(&LA[row * 72 + c4 * 4]) = pa;
      float4 vb = *reinterpret_cast<const float4*>(Bm + (long)(tCol + row) * K + k0 + c4 * 4);
      uint2 pb; pb.x = pack2(vb.x, vb.y); pb.y = pack2(vb.z, vb.w);
      *reinterpret_cast<uint2*>(&LB[row * 72 + c4 * 4]) = pb;
    }
    __syncthreads();
    for (int kk = 0; kk < 2; kk++) {
      bf16x8 af[4], bfr[4];
      for (int m = 0; m < 4; m++)
        af[m]  = *reinterpret_cast<const bf16x8*>(&LA[(wr * 64 + m * 16 + l16) * 72 + kk * 32 + lq * 8]);
      for (int n = 0; n < 4; n++)
        bfr[n] = *reinterpret_cast<const bf16x8*>(&LB[(wc * 64 + n * 16 + l16) * 72 + kk * 32 + lq * 8]);
      for (int m = 0; m < 4; m++)
        for (int n = 0; n < 4; n++)
          acc[m][n] = __builtin_amdgcn_mfma_f32_16x16x32_bf16(af[m], bfr[n], acc[m][n], 0, 0, 0);
    }
  }
  for (int m = 0; m < 4; m++)
    for (int n = 0; n < 4; n++)
      for (int j = 0; j < 4; j++) {
        int row = tRow + wr * 64 + m * 16 + lq * 4 + j;
        int col = tCol + wc * 64 + n * 16 + l16;
        C[(long)row * Nc + col] = f2bf(acc[m][n][j] * cscale);
      }
}

__global__ __launch_bounds__(256) void gemm_qk(
    const float* __restrict__ x,
    const float* __restrict__ Wq, const float* __restrict__ Wk,
    unsigned short* __restrict__ Qb, unsigned short* __restrict__ Kb)
{
  int z = blockIdx.z;
  int b = z >> 3, h = z & 7;
  const float* A  = x + (long)b * 2048 * 1024;
  const float* Bm = (blockIdx.y ? Wk : Wq) + (long)h * 128 * 1024;
  unsigned short* C = (blockIdx.y ? Kb : Qb) + (long)z * 2048 * 128;
  int tRow = blockIdx.x * 128;
  __shared__ __align__(16) unsigned short LA[128 * 72];
  __shared__ __align__(16) unsigned short LB[128 * 72];
  int t = threadIdx.x;
  int l = t & 63, w = t >> 6;
  int wr = w >> 1, wc = w & 1;
  int l16 = l & 15, lq = l >> 4;
  floatx4 acc[4][4] = {};
  const int K = 1024;
  for (int k0 = 0; k0 < K; k0 += 64) {
    __syncthreads();
    for (int i = 0; i < 8; i++) {
      int lin = i * 256 + t;
      int row = lin >> 4;
      int c4  = lin & 15;
      float4 va = *reinterpret_cast<const float4*>(A + (long)(tRow + row) * K + k0 + c4 * 4);
      uint2 pa; pa.x = pack2(va.x, va.y); pa.y = pack2(va.z, va.w);
      *reinterpret_cast<uint2*>(&LA[row * 72 + c4 * 4]) = pa;
      float4 vb = *reinterpret_cast<const float4*>(Bm + (long)row * K + k0 + c4 * 4);
      uint2 pb; pb.x = pack2(vb.x, vb.y); pb.y = pack2(vb.z, vb.w);
      *reinterpret_cast<uint2*>(&LB[row * 72 + c4 * 4]) = pb;
    }
    __syncthreads();
    for (int kk = 0; kk < 2; kk++) {
      bf16x8 af[4], bfr[4];
      for (int m = 0; m < 4; m++)
        af[m]  = *reinterpret_cast<const bf16x8*>(&LA[(wr * 64 + m * 16 + l16) * 72 + kk * 32 + lq * 8]);
      for (int n = 0; n < 4; n++)
        bfr[n] = *reinterpret_cast<const bf16x8*>(&LB[(wc * 64 + n * 16 + l16) * 72 + kk * 32 + lq * 8]);
      for (int m = 0; m < 4; m++)
        for (int n = 0; n < 4; n++)
          acc[m][n] = __builtin_amdgcn_mfma_f32_16x16x32_bf16(af[m], bfr[n], acc[m][n], 0, 0, 0);
    }
  }
  for (int m = 0; m < 4; m++)
    for (int n = 0; n < 4; n++)
      for (int j = 0; j < 4; j++) {
        int row = tRow + wr * 64 + m * 16 + lq * 4 + j;
        int col = wc * 64 + n * 16 + l16;
        C[(long)row * 128 + col] = f2bf(acc[m][n][j]);
      }
}
// ---------------------------------------------------------------------------

// Fused causal relu-attention — QBLK=128 fat q-blocks (34 steps/block, grid
// 512 = one scheduling round at 2 blocks/CU). R14 schedule retained: V via
// global_load_lds; K double-buffered; counted vmcnt; V-wait deferred under
// QK+P; 2 barriers/step. Grid: bid&15 = z (XCD-keyed), (bid>>4)&7 = qp,
// bid>>7 = vb (4 x 256-wide V). LDS: K 2x16K + V 32K + P 16K = 80KB -> 2/CU.
__global__ __launch_bounds__(256, 2) void attn_fused(
    const unsigned short* __restrict__ Qb,
    const unsigned short* __restrict__ Kb,
    const unsigned short* __restrict__ Vtb,
    float* __restrict__ out)
{
  const int bid = blockIdx.x;
  const int z = bid & 15;
  const int qp = (bid >> 4) & 7;
  const int vb = bid >> 7;
  const int b = z >> 3;
  const int t = threadIdx.x;
  const int l = t & 63, w = t >> 6;
  const int l16 = l & 15, lq = l >> 4;
  const int wm = w & 1, wn = w >> 1;   // wm: m-half (32), wn: n-half (64)
  const int swz = l16 & 7;

  __shared__ __align__(16) unsigned short LK[2][64 * 128]; // 2 x 16 KB, swizzled
  __shared__ __align__(16) unsigned short LV[256 * 64];    // 32 KB [v][m] swizzled
  __shared__ __align__(16) unsigned short LP[128 * 64];    // 16 KB [n][m] swizzled

  const unsigned short* Qz = Qb + (long)z * 2048 * 128;
  const unsigned short* Kh = Kb + (long)z * 2048 * 128;
  const unsigned short* Vh = Vtb + (long)z * 1024 * 2048 + (long)(vb * 256) * 2048;

  int ksrc[4], kdst[4];
#pragma unroll
  for (int i = 0; i < 4; i++) {
    int chunk = i * 256 + w * 64 + l;
    int r = chunk >> 4, c = chunk & 15;
    int cs = ((c & 7) ^ (r & 7)) | (c & 8);
    ksrc[i] = r * 128 + cs * 8;
    kdst[i] = (i * 256 + w * 64) * 8;
  }
  int vsrc[8], vdst[8];
#pragma unroll
  for (int i = 0; i < 8; i++) {
    int chunk = i * 256 + w * 64 + l;
    int r = chunk >> 3, c = chunk & 7;
    int cs = c ^ (r & 7);
    vsrc[i] = r * 2048 + cs * 8;
    vdst[i] = (i * 256 + w * 64) * 8;
  }

  int cur = 0;
  for (int hf = 0; hf < 2; hf++) {
    const int qb = hf ? (15 - qp) : qp;        // pairing: 2(qp+1)+2(16-qp) = 34 steps
    const int MT = 2 * qb + 1;                 // last 64-row K tile index
    const unsigned short* Qh = Qz + (long)qb * 128 * 128;
    bf16x8 aQ[4][4];                           // [sn 0..3][ke 0..3]
#pragma unroll
    for (int sn = 0; sn < 4; sn++)
#pragma unroll
      for (int ke = 0; ke < 4; ke++)
        aQ[sn][ke] = *reinterpret_cast<const bf16x8*>(
            Qh + (long)(wn * 64 + sn * 16 + l16) * 128 + ke * 32 + lq * 8);
    floatx4 acc[8][4] = {};                    // [nf 0..7 n][vf 0..3 v]
    // prologue: stage K(0) into LK[cur]
#pragma unroll
    for (int i = 0; i < 4; i++)
      gload16(Kh + ksrc[i], &LK[cur][kdst[i]]);
    for (int M = 0; M <= MT; M++) {
      barrier_v0_lgkm();  // K(M) landed; prev-step LV/LP reads retired
      // issue V(M) gloads (8/wave) -> LV
#pragma unroll
      for (int i = 0; i < 8; i++)
        gload16(Vh + M * 64 + vsrc[i], &LV[vdst[i]]);
      // issue K(M+1) prefetch (4/wave) into alternate buffer
      if (M < MT) {
#pragma unroll
        for (int i = 0; i < 4; i++)
          gload16(Kh + (M + 1) * 8192 + ksrc[i], &LK[cur ^ 1][kdst[i]]);
      }
      // QK: S^T strip = K(32m per wm) . Q^T(64n per wn); V/K latency hides here
      const unsigned short* LKc = LK[cur];
      floatx4 sacc[2][4] = {};
      __builtin_amdgcn_s_setprio(1);
#pragma unroll
      for (int ke = 0; ke < 4; ke++) {
        bf16x8 kf[2];
#pragma unroll
        for (int sm = 0; sm < 2; sm++) {
          int chunk = 4 * ke + lq;
          kf[sm] = *reinterpret_cast<const bf16x8*>(
              &LKc[(wm * 32 + sm * 16 + l16) * 128 +
                   ((((chunk & 7) ^ swz) | (chunk & 8)) * 8)]);
        }
#pragma unroll
        for (int sm = 0; sm < 2; sm++)
#pragma unroll
          for (int sn = 0; sn < 4; sn++)
            sacc[sm][sn] = __builtin_amdgcn_mfma_f32_16x16x32_bf16(
                kf[sm], aQ[sn][ke], sacc[sm][sn], 0, 0, 0);
      }
      __builtin_amdgcn_s_setprio(0);
      // relu (+ diag mask on last two steps), cvt_pk, b64 write to LP[n][m]
      const bool diag = (M >= 2 * qb);
      const int mbase = (M - 2 * qb) * 64;     // m offset rel. to q-block base
#pragma unroll
      for (int sm = 0; sm < 2; sm++)
#pragma unroll
        for (int sn = 0; sn < 4; sn++) {
          floatx4 v = sacc[sm][sn];
          float f0 = fmaxf(v[0], 0.0f), f1 = fmaxf(v[1], 0.0f);
          float f2 = fmaxf(v[2], 0.0f), f3 = fmaxf(v[3], 0.0f);
          if (diag) {
            int mm = mbase + wm * 32 + sm * 16 + lq * 4;
            int nn = wn * 64 + sn * 16 + l16;
            if (mm + 0 > nn) f0 = 0.0f;
            if (mm + 1 > nn) f1 = 0.0f;
            if (mm + 2 > nn) f2 = 0.0f;
            if (mm + 3 > nn) f3 = 0.0f;
          }
          unsigned int p0, p1;
          asm("v_cvt_pk_bf16_f32 %0, %1, %2" : "=v"(p0) : "v"(f0), "v"(f1));
          asm("v_cvt_pk_bf16_f32 %0, %1, %2" : "=v"(p1) : "v"(f2), "v"(f3));
          uint2 pk; pk.x = p0; pk.y = p1;
          int row = wn * 64 + sn * 16 + l16;    // n 0..127
          int cs = wm * 32 + sm * 16 + lq * 4;  // m 0..63
          *reinterpret_cast<uint2*>(
              &LP[row * 64 + (((cs >> 3) ^ (row & 7)) * 8) + (cs & 7)]) = pk;
        }
      // mid barrier: V landed (counted vmcnt leaves K prefetch in flight),
      // P writes visible
      if (M < MT) {
        asm volatile("s_waitcnt vmcnt(4) lgkmcnt(0)" ::: "memory");
      } else {
        asm volatile("s_waitcnt vmcnt(0) lgkmcnt(0)" ::: "memory");
      }
      __builtin_amdgcn_s_barrier();
      __builtin_amdgcn_sched_barrier(0);
      // acc += P(128n x 64m) . V(64m x 64v-slice per wave)
      __builtin_amdgcn_s_setprio(1);
#pragma unroll
      for (int km = 0; km < 2; km++) {
        bf16x8 bV[4];
#pragma unroll
        for (int vf = 0; vf < 4; vf++)
          bV[vf] = *reinterpret_cast<const bf16x8*>(
              &LV[(w * 64 + vf * 16 + l16) * 64 + (((4 * km + lq) ^ swz) * 8)]);
#pragma unroll
        for (int nf = 0; nf < 8; nf++) {
          int row = nf * 16 + l16;
          bf16x8 aP = *reinterpret_cast<const bf16x8*>(
              &LP[row * 64 + (((4 * km + lq) ^ (row & 7)) * 8)]);
#pragma unroll
          for (int vf = 0; vf < 4; vf++)
            acc[nf][vf] = __builtin_amdgcn_mfma_f32_16x16x32_bf16(
                aP, bV[vf], acc[nf][vf], 0, 0, 0);
        }
      }
      __builtin_amdgcn_s_setprio(0);
      cur ^= 1;
    }  // M
    // epilogue: atomic head-sum into out (pre-initialized to x)
#pragma unroll
    for (int nf = 0; nf < 8; nf++)
#pragma unroll
      for (int vf = 0; vf < 4; vf++)
#pragma unroll
        for (int j = 0; j < 4; j++) {
          int n = qb * 128 + nf * 16 + lq * 4 + j;
          int v = vb * 256 + w * 64 + vf * 16 + l16;
          long idx = ((long)b * 2048 + n) * 1024 + v;
          unsafeAtomicAdd(&out[idx], acc[nf][vf][j]);
        }
  }  // hf
}

extern "C" void kernel_launch(void* const* d_in, const int* in_sizes, int n_in,
                              void* d_out, int out_size, void* d_ws, size_t ws_size,
                              hipStream_t stream) {
  const float* x  = (const float*)d_in[0];
  const float* Wq = (const float*)d_in[1];
  const float* Wk = (const float*)d_in[2];
  const float* Wv = (const float*)d_in[3];
  float* out = (float*)d_out;
  const size_t MB = 1u << 20;
  dim3 blk(256);

  if (ws_size >= 104 * MB) {
    unsigned short* Vtb  = (unsigned short*)d_ws;
    unsigned short* Wqkb = (unsigned short*)d_ws;  // alias, dead before Vt write
    unsigned short* Qb   = (unsigned short*)((char*)d_ws + 64 * MB);
    unsigned short* Kb   = (unsigned short*)((char*)d_ws + 72 * MB);
    unsigned short* xb   = (unsigned short*)((char*)d_ws + 80 * MB);
    unsigned short* Wvb  = (unsigned short*)((char*)d_ws + 88 * MB);

    convert_all<<<dim3(2048), blk, 0, stream>>>(
        (const float4*)x, (const float4*)Wq, (const float4*)Wk, (const float4*)Wv,
        (uint2*)xb, (uint2*)Wqkb, (uint2*)Wvb, (float4*)out);
    gemm8<<<dim3(640), dim3(512), 0, stream>>>(xb, Wqkb, Wvb, Qb, Kb, Vtb);
    attn_fused<<<dim3(512), blk, 0, stream>>>(Qb, Kb, Vtb, out);
  } else {
    unsigned short* Qb  = (unsigned short*)d_ws;
    unsigned short* Kb  = Qb + (size_t)2 * 8 * 2048 * 128;
    unsigned short* Vtb = Kb + (size_t)2 * 8 * 2048 * 128;
    init_out<<<dim3(1024), blk, 0, stream>>>(
        (const float4*)x, (float4*)out, 2 * 2048 * 1024 / 4);
    gemm_qk<<<dim3(16, 2, 16), blk, 0, stream>>>(x, Wq, Wk, Qb, Kb);
    gemm_bt<<<dim3(8, 16, 16), blk, 0, stream>>>(
        Wv, 0, (long)1024 * 1024, x, (long)2048 * 1024, 0,
        Vtb, (long)1024 * 2048, 1024, 2048, 1024, 8, 1.0f / 2048.0f);
    attn_fused<<<dim3(512), blk, 0, stream>>>(Qb, Kb, Vtb, out);
  }
}

// Round 21
// 276.979 us; speedup vs baseline: 1.5363x; 1.5363x over previous
//
#include <hip/hip_runtime.h>

typedef __attribute__((ext_vector_type(8))) short bf16x8;
typedef __attribute__((ext_vector_type(4))) float floatx4;

__device__ __forceinline__ unsigned short f2bf(float f) {
  unsigned int u = __builtin_bit_cast(unsigned int, f);
  unsigned int r = (u + 0x7fffu + ((u >> 16) & 1u)) >> 16;
  return (unsigned short)r;
}

__device__ __forceinline__ unsigned int pack2(float a, float b) {
  return (unsigned int)f2bf(a) | ((unsigned int)f2bf(b) << 16);
}

__device__ __forceinline__ void gload16(const void* g, void* l) {
  __builtin_amdgcn_global_load_lds(
      (__attribute__((address_space(1))) void*)g,
      (__attribute__((address_space(3))) void*)l, 16, 0, 0);
}

// full-drain barrier (loop top): K(M) prefetch + prev-step LDS reads done.
__device__ __forceinline__ void barrier_v0_lgkm() {
  asm volatile("s_waitcnt vmcnt(0) lgkmcnt(0)" ::: "memory");
  __builtin_amdgcn_s_barrier();
  __builtin_amdgcn_sched_barrier(0);
}

// out = x (residual init), plus f32->bf16 of x, [Wq;Wk] concat, Wv (scaled 1/N)
__global__ __launch_bounds__(256) void convert_all(
    const float4* __restrict__ x4,
    const float4* __restrict__ wq4, const float4* __restrict__ wk4,
    const float4* __restrict__ wv4,
    uint2* __restrict__ xb4, uint2* __restrict__ wqkb4, uint2* __restrict__ wvb4,
    float4* __restrict__ out4)
{
  const int NX = 2 * 2048 * 1024 / 4;
  const int NQK = 8 * 256 * 1024 / 4;
  const int NV = 8 * 1024 * 1024 / 4;
  const int total = NX + NQK + NV;
  const float inv_n = 1.0f / 2048.0f;
  for (int i = blockIdx.x * 256 + threadIdx.x; i < total; i += gridDim.x * 256) {
    float4 f; uint2* dst;
    if (i < NX) {
      f = x4[i]; dst = &xb4[i];
      out4[i] = f;                         // residual init fused here
    } else if (i < NX + NQK) {
      int j = i - NX;
      int c = j & 255;
      int row = j >> 8;
      int h = row >> 8, r = row & 255;
      f = (r < 128) ? wq4[(h * 128 + r) * 256 + c] : wk4[(h * 128 + r - 128) * 256 + c];
      dst = &wqkb4[j];
    } else {
      int j = i - NX - NQK;
      f = wv4[j];
      f.x *= inv_n; f.y *= inv_n; f.z *= inv_n; f.w *= inv_n;  // fold 1/N into V
      dst = &wvb4[j];
    }
    uint2 p; p.x = pack2(f.x, f.y); p.y = pack2(f.z, f.w);
    *dst = p;
  }
}

// init for fallback path
__global__ __launch_bounds__(256) void init_out(const float4* __restrict__ x,
                                                float4* __restrict__ out, int n4) {
  for (int i = blockIdx.x * 256 + threadIdx.x; i < n4; i += gridDim.x * 256)
    out[i] = x[i];
}

// ============ 256x256 8-phase GEMM (guide §5.5 T2+T3+T4+T5 template) ========
__global__ __launch_bounds__(512, 2) void gemm8(
    const unsigned short* __restrict__ xb,
    const unsigned short* __restrict__ Wqkb,
    const unsigned short* __restrict__ Wvb,
    unsigned short* __restrict__ Qb, unsigned short* __restrict__ Kb,
    unsigned short* __restrict__ Vtb)
{
  __shared__ __align__(16) unsigned short LA[2][2][128 * 64]; // [dbuf][half]
  __shared__ __align__(16) unsigned short LB[2][2][128 * 64];
  const int bid = blockIdx.x;
  const int t = threadIdx.x;
  const int l = t & 63, w = t >> 6;
  const int l16 = l & 15, lq = l >> 4;
  const int wm = w & 1, wn = w >> 1;

  const unsigned short *Ag, *Bg;
  unsigned short *C0, *C1; long ld0, ld1; int split;
  if (bid < 128) {
    int z = bid & 15, br = bid >> 4;
    int b = z >> 3, h = z & 7;
    Ag = xb + (long)b * 2048 * 1024 + (long)br * 256 * 1024;
    Bg = Wqkb + (long)h * 256 * 1024;
    C0 = Qb + (long)z * 2048 * 128 + (long)br * 256 * 128;
    C1 = Kb + (long)z * 2048 * 128 + (long)br * 256 * 128;
    ld0 = 128; ld1 = 128; split = 128;
  } else {
    int v = bid - 128;
    int z = v & 15, rc = v >> 4;
    int bx = rc & 3, by = rc >> 2;
    int b = z >> 3, h = z & 7;
    Ag = Wvb + (long)h * 1024 * 1024 + (long)bx * 256 * 1024;
    Bg = xb + (long)b * 2048 * 1024 + (long)by * 256 * 1024;
    C0 = Vtb + (long)z * 1024 * 2048 + (long)bx * 256 * 2048 + by * 256;
    C1 = C0; ld0 = 2048; ld1 = 2048; split = 1 << 30;
  }

  int rr[2], kk[2], cb[2];
#pragma unroll
  for (int i = 0; i < 2; i++) {
    int c = i * 512 + t;
    rr[i] = c >> 3;
    int k8 = c & 7;
    kk[i] = (k8 ^ (((rr[i] >> 2) & 3) << 1)) * 8;
    cb[i] = (i * 512 + w * 64) * 8;
  }
  auto STAGE = [&](const unsigned short* OP, unsigned short* dstbuf, int kt, int half) {
#pragma unroll
    for (int i = 0; i < 2; i++)
      gload16(OP + (long)(half * 128 + rr[i]) * 1024 + kt * 64 + kk[i],
              dstbuf + cb[i]);
  };
  auto RD = [&](const unsigned short* buf, int fr, int ks) -> bf16x8 {
    int r = fr * 16 + l16;
    int k8 = ks * 4 + lq;
    int k8s = k8 ^ (((r >> 2) & 3) << 1);
    return *reinterpret_cast<const bf16x8*>(buf + r * 64 + k8s * 8);
  };

  floatx4 acc[8][4] = {};
  const int bfr = (wn & 1) * 4;

  STAGE(Ag, LA[0][0], 0, 0); STAGE(Ag, LA[0][1], 0, 1);
  STAGE(Bg, LB[0][0], 0, 0); STAGE(Bg, LB[0][1], 0, 1);
  asm volatile("s_waitcnt vmcnt(0)" ::: "memory");
  __builtin_amdgcn_s_barrier();
  __builtin_amdgcn_sched_barrier(0);

  for (int kt = 0; kt < 16; kt++) {
    const int d = kt & 1, nd = d ^ 1;
    const unsigned short* myA = LA[d][wm];
    const unsigned short* myB = LB[d][wn >> 1];
    const bool more = (kt + 1 < 16);
    bf16x8 a0[4][2], a1[4][2], b0[2][2], b1[2][2];

#pragma unroll
    for (int fr = 0; fr < 4; fr++)
#pragma unroll
      for (int ks = 0; ks < 2; ks++) a0[fr][ks] = RD(myA, fr, ks);
#pragma unroll
    for (int fc = 0; fc < 2; fc++)
#pragma unroll
      for (int ks = 0; ks < 2; ks++) b0[fc][ks] = RD(myB, bfr + fc, ks);
    if (more) { STAGE(Ag, LA[nd][0], kt + 1, 0); STAGE(Ag, LA[nd][1], kt + 1, 1); }
    __builtin_amdgcn_s_barrier();
    asm volatile("s_waitcnt lgkmcnt(0)" ::: "memory");
    __builtin_amdgcn_sched_barrier(0);
    __builtin_amdgcn_s_setprio(1);
#pragma unroll
    for (int fr = 0; fr < 4; fr++)
#pragma unroll
      for (int fc = 0; fc < 2; fc++)
#pragma unroll
        for (int ks = 0; ks < 2; ks++)
          acc[fr][fc] = __builtin_amdgcn_mfma_f32_16x16x32_bf16(
              a0[fr][ks], b0[fc][ks], acc[fr][fc], 0, 0, 0);
    __builtin_amdgcn_s_setprio(0);
    __builtin_amdgcn_s_barrier();

#pragma unroll
    for (int fc = 0; fc < 2; fc++)
#pragma unroll
      for (int ks = 0; ks < 2; ks++) b1[fc][ks] = RD(myB, bfr + 2 + fc, ks);
    if (more) { STAGE(Bg, LB[nd][0], kt + 1, 0); STAGE(Bg, LB[nd][1], kt + 1, 1); }
    __builtin_amdgcn_s_barrier();
    asm volatile("s_waitcnt lgkmcnt(0)" ::: "memory");
    __builtin_amdgcn_sched_barrier(0);
    __builtin_amdgcn_s_setprio(1);
#pragma unroll
    for (int fr = 0; fr < 4; fr++)
#pragma unroll
      for (int fc = 0; fc < 2; fc++)
#pragma unroll
        for (int ks = 0; ks < 2; ks++)
          acc[fr][2 + fc] = __builtin_amdgcn_mfma_f32_16x16x32_bf16(
              a0[fr][ks], b1[fc][ks], acc[fr][2 + fc], 0, 0, 0);
    __builtin_amdgcn_s_setprio(0);
    __builtin_amdgcn_s_barrier();

#pragma unroll
    for (int fr = 0; fr < 4; fr++)
#pragma unroll
      for (int ks = 0; ks < 2; ks++) a1[fr][ks] = RD(myA, 4 + fr, ks);
    __builtin_amdgcn_s_barrier();
    asm volatile("s_waitcnt lgkmcnt(0)" ::: "memory");
    __builtin_amdgcn_sched_barrier(0);
    __builtin_amdgcn_s_setprio(1);
#pragma unroll
    for (int fr = 0; fr < 4; fr++)
#pragma unroll
      for (int fc = 0; fc < 2; fc++)
#pragma unroll
        for (int ks = 0; ks < 2; ks++)
          acc[4 + fr][fc] = __builtin_amdgcn_mfma_f32_16x16x32_bf16(
              a1[fr][ks], b0[fc][ks], acc[4 + fr][fc], 0, 0, 0);
    __builtin_amdgcn_s_setprio(0);
    __builtin_amdgcn_s_barrier();

    __builtin_amdgcn_s_setprio(1);
#pragma unroll
    for (int fr = 0; fr < 4; fr++)
#pragma unroll
      for (int fc = 0; fc < 2; fc++)
#pragma unroll
        for (int ks = 0; ks < 2; ks++)
          acc[4 + fr][2 + fc] = __builtin_amdgcn_mfma_f32_16x16x32_bf16(
              a1[fr][ks], b1[fc][ks], acc[4 + fr][2 + fc], 0, 0, 0);
    __builtin_amdgcn_s_setprio(0);
    asm volatile("s_waitcnt vmcnt(0)" ::: "memory");
    __builtin_amdgcn_s_barrier();
    __builtin_amdgcn_sched_barrier(0);
  }

#pragma unroll
  for (int fr = 0; fr < 8; fr++)
#pragma unroll
    for (int fc = 0; fc < 4; fc++)
#pragma unroll
      for (int j = 0; j < 4; j++) {
        int row = wm * 128 + fr * 16 + lq * 4 + j;
        int col = wn * 64 + fc * 16 + l16;
        unsigned short v = f2bf(acc[fr][fc][j]);
        if (col < split) C0[(long)row * ld0 + col] = v;
        else             C1[(long)row * ld1 + (col - split)] = v;
      }
}
// ===========================================================================

// ---------------- fallback (f32-staging) GEMMs, used if ws too small --------
__global__ __launch_bounds__(256) void gemm_bt(
    const float* __restrict__ Abase, long sAb, long sAh,
    const float* __restrict__ Bbase, long sBb, long sBh,
    unsigned short* __restrict__ Cbase, long sC,
    int M, int Nc, int K, int H, float cscale)
{
  int z = blockIdx.z;
  int b = z / H, h = z % H;
  const float* A  = Abase + (long)b * sAb + (long)h * sAh;
  const float* Bm = Bbase + (long)b * sBb + (long)h * sBh;
  unsigned short* C = Cbase + (long)z * sC;
  int tRow = blockIdx.x * 128;
  int tCol = blockIdx.y * 128;
  __shared__ __align__(16) unsigned short LA[128 * 72];
  __shared__ __align__(16) unsigned short LB[128 * 72];
  int t = threadIdx.x;
  int l = t & 63, w = t >> 6;
  int wr = w >> 1, wc = w & 1;
  int l16 = l & 15, lq = l >> 4;
  floatx4 acc[4][4] = {};
  for (int k0 = 0; k0 < K; k0 += 64) {
    __syncthreads();
    for (int i = 0; i < 8; i++) {
      int lin = i * 256 + t;
      int row = lin >> 4;
      int c4  = lin & 15;
      float4 va = *reinterpret_cast<const float4*>(A + (long)(tRow + row) * K + k0 + c4 * 4);
      uint2 pa; pa.x = pack2(va.x, va.y); pa.y = pack2(va.z, va.w);
      *reinterpret_cast<uint2*>(&LA[row * 72 + c4 * 4]) = pa;
      float4 vb = *reinterpret_cast<const float4*>(Bm + (long)(tCol + row) * K + k0 + c4 * 4);
      uint2 pb; pb.x = pack2(vb.x, vb.y); pb.y = pack2(vb.z, vb.w);
      *reinterpret_cast<uint2*>(&LB[row * 72 + c4 * 4]) = pb;
    }
    __syncthreads();
    for (int kk = 0; kk < 2; kk++) {
      bf16x8 af[4], bfr[4];
      for (int m = 0; m < 4; m++)
        af[m]  = *reinterpret_cast<const bf16x8*>(&LA[(wr * 64 + m * 16 + l16) * 72 + kk * 32 + lq * 8]);
      for (int n = 0; n < 4; n++)
        bfr[n] = *reinterpret_cast<const bf16x8*>(&LB[(wc * 64 + n * 16 + l16) * 72 + kk * 32 + lq * 8]);
      for (int m = 0; m < 4; m++)
        for (int n = 0; n < 4; n++)
          acc[m][n] = __builtin_amdgcn_mfma_f32_16x16x32_bf16(af[m], bfr[n], acc[m][n], 0, 0, 0);
    }
  }
  for (int m = 0; m < 4; m++)
    for (int n = 0; n < 4; n++)
      for (int j = 0; j < 4; j++) {
        int row = tRow + wr * 64 + m * 16 + lq * 4 + j;
        int col = tCol + wc * 64 + n * 16 + l16;
        C[(long)row * Nc + col] = f2bf(acc[m][n][j] * cscale);
      }
}

__global__ __launch_bounds__(256) void gemm_qk(
    const float* __restrict__ x,
    const float* __restrict__ Wq, const float* __restrict__ Wk,
    unsigned short* __restrict__ Qb, unsigned short* __restrict__ Kb)
{
  int z = blockIdx.z;
  int b = z >> 3, h = z & 7;
  const float* A  = x + (long)b * 2048 * 1024;
  const float* Bm = (blockIdx.y ? Wk : Wq) + (long)h * 128 * 1024;
  unsigned short* C = (blockIdx.y ? Kb : Qb) + (long)z * 2048 * 128;
  int tRow = blockIdx.x * 128;
  __shared__ __align__(16) unsigned short LA[128 * 72];
  __shared__ __align__(16) unsigned short LB[128 * 72];
  int t = threadIdx.x;
  int l = t & 63, w = t >> 6;
  int wr = w >> 1, wc = w & 1;
  int l16 = l & 15, lq = l >> 4;
  floatx4 acc[4][4] = {};
  const int K = 1024;
  for (int k0 = 0; k0 < K; k0 += 64) {
    __syncthreads();
    for (int i = 0; i < 8; i++) {
      int lin = i * 256 + t;
      int row = lin >> 4;
      int c4  = lin & 15;
      float4 va = *reinterpret_cast<const float4*>(A + (long)(tRow + row) * K + k0 + c4 * 4);
      uint2 pa; pa.x = pack2(va.x, va.y); pa.y = pack2(va.z, va.w);
      *reinterpret_cast<uint2*>(&LA[row * 72 + c4 * 4]) = pa;
      float4 vb = *reinterpret_cast<const float4*>(Bm + (long)row * K + k0 + c4 * 4);
      uint2 pb; pb.x = pack2(vb.x, vb.y); pb.y = pack2(vb.z, vb.w);
      *reinterpret_cast<uint2*>(&LB[row * 72 + c4 * 4]) = pb;
    }
    __syncthreads();
    for (int kk = 0; kk < 2; kk++) {
      bf16x8 af[4], bfr[4];
      for (int m = 0; m < 4; m++)
        af[m]  = *reinterpret_cast<const bf16x8*>(&LA[(wr * 64 + m * 16 + l16) * 72 + kk * 32 + lq * 8]);
      for (int n = 0; n < 4; n++)
        bfr[n] = *reinterpret_cast<const bf16x8*>(&LB[(wc * 64 + n * 16 + l16) * 72 + kk * 32 + lq * 8]);
      for (int m = 0; m < 4; m++)
        for (int n = 0; n < 4; n++)
          acc[m][n] = __builtin_amdgcn_mfma_f32_16x16x32_bf16(af[m], bfr[n], acc[m][n], 0, 0, 0);
    }
  }
  for (int m = 0; m < 4; m++)
    for (int n = 0; n < 4; n++)
      for (int j = 0; j < 4; j++) {
        int row = tRow + wr * 64 + m * 16 + lq * 4 + j;
        int col = wc * 64 + n * 16 + l16;
        C[(long)row * 128 + col] = f2bf(acc[m][n][j]);
      }
}
// ---------------------------------------------------------------------------

// Fused causal relu-attention — best-known config (R14/R16/R19, 167 µs):
// V through global_load_lds LDS; K double-buffered with counted vmcnt; the
// V-wait deferred under QK+P; 2 barriers/step. Grid 1024: bid&15 = z
// (XCD-clustered), (bid>>4)&15 = pair, bid>>8 = vb (4 x 256-wide V).
// LDS: K 2x16K + V 32K + P 8K = 72KB -> exactly 2 blocks/CU (L2 live-set fit).
// Structural note: QBLK/KVBLK/vb variations all refuted on-device (R12/R17/
// R18/R20 — VGPR cap at 256 threads forces exactly this working set).
__global__ __launch_bounds__(256, 2) void attn_fused(
    const unsigned short* __restrict__ Qb,
    const unsigned short* __restrict__ Kb,
    const unsigned short* __restrict__ Vtb,
    float* __restrict__ out)
{
  const int bid = blockIdx.x;
  const int z = bid & 15;
  const int pair = (bid >> 4) & 15;
  const int vb = bid >> 8;
  const int b = z >> 3;
  const int t = threadIdx.x;
  const int l = t & 63, w = t >> 6;
  const int l16 = l & 15, lq = l >> 4;
  const int wm = w & 1, wn = w >> 1;   // 2x2 wave split for QK^T
  const int swz = l16 & 7;

  __shared__ __align__(16) unsigned short LK[2][64 * 128]; // 2 x 16 KB, swizzled
  __shared__ __align__(16) unsigned short LV[256 * 64];    // 32 KB [v][m] swizzled
  __shared__ __align__(16) unsigned short LP[64 * 64];     //  8 KB [n][m] swizzled

  const unsigned short* Qz = Qb + (long)z * 2048 * 128;
  const unsigned short* Kh = Kb + (long)z * 2048 * 128;
  const unsigned short* Vh = Vtb + (long)z * 1024 * 2048 + (long)(vb * 256) * 2048;

  int ksrc[4], kdst[4];
#pragma unroll
  for (int i = 0; i < 4; i++) {
    int chunk = i * 256 + w * 64 + l;
    int r = chunk >> 4, c = chunk & 15;
    int cs = ((c & 7) ^ (r & 7)) | (c & 8);
    ksrc[i] = r * 128 + cs * 8;
    kdst[i] = (i * 256 + w * 64) * 8;
  }
  int vsrc[8], vdst[8];
#pragma unroll
  for (int i = 0; i < 8; i++) {
    int chunk = i * 256 + w * 64 + l;
    int r = chunk >> 3, c = chunk & 7;
    int cs = c ^ (r & 7);
    vsrc[i] = r * 2048 + cs * 8;
    vdst[i] = (i * 256 + w * 64) * 8;
  }

  int cur = 0;
  for (int hf = 0; hf < 2; hf++) {
    const int T = hf ? (31 - pair) : pair;
    const unsigned short* Qh = Qz + (long)T * 64 * 128;
    bf16x8 aQ[2][4];
#pragma unroll
    for (int sn = 0; sn < 2; sn++)
#pragma unroll
      for (int ke = 0; ke < 4; ke++)
        aQ[sn][ke] = *reinterpret_cast<const bf16x8*>(
            Qh + (long)(wn * 32 + sn * 16 + l16) * 128 + ke * 32 + lq * 8);
    floatx4 acc[4][4] = {};
#pragma unroll
    for (int i = 0; i < 4; i++)
      gload16(Kh + ksrc[i], &LK[cur][kdst[i]]);
    for (int M = 0; M <= T; M++) {
      barrier_v0_lgkm();  // K(M) landed; prev-step LV/LP reads retired
#pragma unroll
      for (int i = 0; i < 8; i++)
        gload16(Vh + M * 64 + vsrc[i], &LV[vdst[i]]);
      if (M < T) {
#pragma unroll
        for (int i = 0; i < 4; i++)
          gload16(Kh + (M + 1) * 8192 + ksrc[i], &LK[cur ^ 1][kdst[i]]);
      }
      // QK immediately — LK[cur] synced at loop top; V/K latency hides here
      const unsigned short* LKc = LK[cur];
      floatx4 sacc[2][2] = {{{}, {}}, {{}, {}}};
      __builtin_amdgcn_s_setprio(1);
#pragma unroll
      for (int ke = 0; ke < 4; ke++) {
        bf16x8 kf[2];
#pragma unroll
        for (int sm = 0; sm < 2; sm++) {
          int chunk = 4 * ke + lq;
          kf[sm] = *reinterpret_cast<const bf16x8*>(
              &LKc[(wm * 32 + sm * 16 + l16) * 128 +
                   ((((chunk & 7) ^ swz) | (chunk & 8)) * 8)]);
        }
#pragma unroll
        for (int sm = 0; sm < 2; sm++)
#pragma unroll
          for (int sn = 0; sn < 2; sn++)
            sacc[sm][sn] = __builtin_amdgcn_mfma_f32_16x16x32_bf16(
                kf[sm], aQ[sn][ke], sacc[sm][sn], 0, 0, 0);
      }
      __builtin_amdgcn_s_setprio(0);
      const bool diag = (M == T);
#pragma unroll
      for (int sm = 0; sm < 2; sm++)
#pragma unroll
        for (int sn = 0; sn < 2; sn++) {
          floatx4 v = sacc[sm][sn];
          float f0 = fmaxf(v[0], 0.0f), f1 = fmaxf(v[1], 0.0f);
          float f2 = fmaxf(v[2], 0.0f), f3 = fmaxf(v[3], 0.0f);
          if (diag) {
            int mm = wm * 32 + sm * 16 + lq * 4;
            int nn = wn * 32 + sn * 16 + l16;
            if (mm + 0 > nn) f0 = 0.0f;
            if (mm + 1 > nn) f1 = 0.0f;
            if (mm + 2 > nn) f2 = 0.0f;
            if (mm + 3 > nn) f3 = 0.0f;
          }
          unsigned int p0, p1;
          asm("v_cvt_pk_bf16_f32 %0, %1, %2" : "=v"(p0) : "v"(f0), "v"(f1));
          asm("v_cvt_pk_bf16_f32 %0, %1, %2" : "=v"(p1) : "v"(f2), "v"(f3));
          uint2 pk; pk.x = p0; pk.y = p1;
          int row = wn * 32 + sn * 16 + l16;
          int cs = wm * 32 + sm * 16 + lq * 4;
          *reinterpret_cast<uint2*>(
              &LP[row * 64 + (((cs >> 3) ^ (row & 7)) * 8) + (cs & 7)]) = pk;
        }
      // mid barrier: V landed (counted vmcnt leaves K prefetch in flight),
      // P writes visible
      if (M < T) {
        asm volatile("s_waitcnt vmcnt(4) lgkmcnt(0)" ::: "memory");
      } else {
        asm volatile("s_waitcnt vmcnt(0) lgkmcnt(0)" ::: "memory");
      }
      __builtin_amdgcn_s_barrier();
      __builtin_amdgcn_sched_barrier(0);
      __builtin_amdgcn_s_setprio(1);
#pragma unroll
      for (int km = 0; km < 2; km++) {
        bf16x8 aP[4], bV[4];
#pragma unroll
        for (int nf = 0; nf < 4; nf++)
          aP[nf] = *reinterpret_cast<const bf16x8*>(
              &LP[(nf * 16 + l16) * 64 + (((4 * km + lq) ^ swz) * 8)]);
#pragma unroll
        for (int vf = 0; vf < 4; vf++)
          bV[vf] = *reinterpret_cast<const bf16x8*>(
              &LV[(w * 64 + vf * 16 + l16) * 64 + (((4 * km + lq) ^ swz) * 8)]);
#pragma unroll
        for (int nf = 0; nf < 4; nf++)
#pragma unroll
          for (int vf = 0; vf < 4; vf++)
            acc[nf][vf] = __builtin_amdgcn_mfma_f32_16x16x32_bf16(
                aP[nf], bV[vf], acc[nf][vf], 0, 0, 0);
      }
      __builtin_amdgcn_s_setprio(0);
      cur ^= 1;
    }  // M
#pragma unroll
    for (int nf = 0; nf < 4; nf++)
#pragma unroll
      for (int vf = 0; vf < 4; vf++)
#pragma unroll
        for (int j = 0; j < 4; j++) {
          int n = T * 64 + nf * 16 + lq * 4 + j;
          int v = vb * 256 + w * 64 + vf * 16 + l16;
          long idx = ((long)b * 2048 + n) * 1024 + v;
          unsafeAtomicAdd(&out[idx], acc[nf][vf][j]);
        }
  }  // hf
}

extern "C" void kernel_launch(void* const* d_in, const int* in_sizes, int n_in,
                              void* d_out, int out_size, void* d_ws, size_t ws_size,
                              hipStream_t stream) {
  const float* x  = (const float*)d_in[0];
  const float* Wq = (const float*)d_in[1];
  const float* Wk = (const float*)d_in[2];
  const float* Wv = (const float*)d_in[3];
  float* out = (float*)d_out;
  const size_t MB = 1u << 20;
  dim3 blk(256);

  if (ws_size >= 104 * MB) {
    unsigned short* Vtb  = (unsigned short*)d_ws;
    unsigned short* Wqkb = (unsigned short*)d_ws;  // alias, dead before Vt write
    unsigned short* Qb   = (unsigned short*)((char*)d_ws + 64 * MB);
    unsigned short* Kb   = (unsigned short*)((char*)d_ws + 72 * MB);
    unsigned short* xb   = (unsigned short*)((char*)d_ws + 80 * MB);
    unsigned short* Wvb  = (unsigned short*)((char*)d_ws + 88 * MB);

    convert_all<<<dim3(2048), blk, 0, stream>>>(
        (const float4*)x, (const float4*)Wq, (const float4*)Wk, (const float4*)Wv,
        (uint2*)xb, (uint2*)Wqkb, (uint2*)Wvb, (float4*)out);
    gemm8<<<dim3(640), dim3(512), 0, stream>>>(xb, Wqkb, Wvb, Qb, Kb, Vtb);
    attn_fused<<<dim3(1024), blk, 0, stream>>>(Qb, Kb, Vtb, out);
  } else {
    unsigned short* Qb  = (unsigned short*)d_ws;
    unsigned short* Kb  = Qb + (size_t)2 * 8 * 2048 * 128;
    unsigned short* Vtb = Kb + (size_t)2 * 8 * 2048 * 128;
    init_out<<<dim3(1024), blk, 0, stream>>>(
        (const float4*)x, (float4*)out, 2 * 2048 * 1024 / 4);
    gemm_qk<<<dim3(16, 2, 16), blk, 0, stream>>>(x, Wq, Wk, Qb, Kb);
    gemm_bt<<<dim3(8, 16, 16), blk, 0, stream>>>(
        Wv, 0, (long)1024 * 1024, x, (long)2048 * 1024, 0,
        Vtb, (long)1024 * 2048, 1024, 2048, 1024, 8, 1.0f / 2048.0f);
    attn_fused<<<dim3(1024), blk, 0, stream>>>(Qb, Kb, Vtb, out);
  }
}